// Round 3
// baseline (340.625 us; speedup 1.0000x reference)
//
#include <hip/hip_runtime.h>
#include <hip/hip_bf16.h>
#include <stdint.h>

typedef __bf16 bf16;
typedef __attribute__((ext_vector_type(8))) __bf16 bf16x8;
typedef __attribute__((ext_vector_type(4))) float f32x4;

#define KREAL 784
#define NTILES 25            // 25 k-tiles of 32
#define TROW   40            // row length in elements within a k-tile (32 + 8 pad)
#define TILE_ELEMS (256 * TROW)   // 10240 elements = 20 KB per k-tile

#define GLOBAL_AS __attribute__((address_space(1)))
#define LDS_AS    __attribute__((address_space(3)))

// ---------------------------------------------------------------------------
// Prep: fold 3x3 VALID cross-correlation into w1, emit k-tiled, row-padded:
//   W[tile][n][kk]  kk in [0,40), value for k = tile*32+kk when kk<32 & k<784,
//   else 0. 80 B row stride -> ds_read_b128 is 2-way-only on banks (free),
//   and the pad lives in GLOBAL memory so global_load_lds's (wave-uniform
//   base + lane*16) rule still sees one contiguous region.
// ---------------------------------------------------------------------------
__global__ __launch_bounds__(256) void prep_w1tt(const float* __restrict__ w_conv,
                                                 const float* __restrict__ w1,
                                                 bf16* __restrict__ W) {
    const int tile = blockIdx.x / TROW;
    const int kk   = blockIdx.x % TROW;
    const int n    = threadIdx.x;
    const int k    = tile * 32 + kk;
    float s = 0.0f;
    if (kk < 32 && k < KREAL) {
        const int r = k / 28, c = k % 28;
        #pragma unroll
        for (int di = 0; di < 3; ++di) {
            const int i = r - di;
            if (i < 0 || i >= 26) continue;
            #pragma unroll
            for (int dj = 0; dj < 3; ++dj) {
                const int j = c - dj;
                if (j < 0 || j >= 26) continue;
                s += w_conv[di * 3 + dj] * w1[(i * 26 + j) * 256 + n];
            }
        }
    }
    W[(size_t)tile * TILE_ELEMS + n * TROW + kk] = (bf16)s;
}

// ---------------------------------------------------------------------------
// Fused: out = relu(x @ W1' + b1) @ w2 + b2
// M=64/block (grid 1024 -> 4 blocks/CU, 16 waves/CU), N=256 (full), BK=32.
// TLP is the lever this round: R1 measured OccupancyPercent=22% (grid-capped
// at 2 blocks/CU); the per-iter barrier's vmcnt(0) drain idled half the CU.
// With 4 independent blocks/CU, three blocks stream through any one block's
// barrier drain. LDS = exactly 2 x 20 KB = 40960 B so 4 blocks fit 160 KB.
//   A: global -> float regs, prefetched one iter ahead, cvt after MFMAs.
//   B: global_load_lds DMA into double-buffered Bs, issued one iter ahead.
// Epilogue constants (w2/b1/b2, L1/L2-hot) read straight from global.
// ---------------------------------------------------------------------------
__global__ __launch_bounds__(256, 4) void fused_mlp(
    const float* __restrict__ x,    // (65536, 784)
    const bf16*  __restrict__ W,    // k-tiled padded W1' (25*10240 bf16)
    const float* __restrict__ b1,   // (256)
    const float* __restrict__ w2,   // (256, 10)
    const float* __restrict__ b2,   // (10)
    float* __restrict__ out)        // (65536, 10)
{
    __shared__ bf16 Bs[2][TILE_ELEMS];   // 2 x 20 KB = 40960 B exactly

    const int t    = threadIdx.x;
    const int wave = t >> 6;
    const int lane = t & 63;
    const int c    = lane & 15;   // MFMA col / A-row within 16-tile
    const int q    = lane >> 4;   // MFMA quad (k-chunk selector)

    const int row0 = blockIdx.x * 64;

    // A: wave w owns rows w*16 .. w*16+15; lane (c,q) reads row c, k-chunk q*8
    const float* arow0 = x + (size_t)(row0 + wave * 16 + c) * KREAL + q * 8;
    // B DMA: wave w, instr j stages elements [(w*5+j)*512, +512) of the tile
    const bf16* bsrc = W + (size_t)(wave * 5) * 512 + lane * 8;

    f32x4 acc[16];
    #pragma unroll
    for (int nt = 0; nt < 16; ++nt)
        acc[nt] = (f32x4){0.f, 0.f, 0.f, 0.f};

    // ---- prologue: A(0) loads, DMA tile 0, cvt A(0) ----
    float4 f0a = *(const float4*)arow0, f0b = *(const float4*)(arow0 + 4);
    #pragma unroll
    for (int j = 0; j < 5; ++j) {
        __builtin_amdgcn_global_load_lds(
            (const GLOBAL_AS void*)(bsrc + j * 512),
            (LDS_AS void*)((char*)&Bs[0][0] + (wave * 5 + j) * 1024), 16, 0, 0);
    }
    bf16x8 a0;
    a0[0] = (bf16)f0a.x; a0[1] = (bf16)f0a.y; a0[2] = (bf16)f0a.z; a0[3] = (bf16)f0a.w;
    a0[4] = (bf16)f0b.x; a0[5] = (bf16)f0b.y; a0[6] = (bf16)f0b.z; a0[7] = (bf16)f0b.w;

    asm volatile("s_waitcnt vmcnt(0)" ::: "memory");  // tile 0 resident
    __builtin_amdgcn_sched_barrier(0);
    __builtin_amdgcn_s_barrier();
    __builtin_amdgcn_sched_barrier(0);

    #pragma unroll 1
    for (int it = 0; it < NTILES; ++it) {
        const int  cur  = it & 1;
        const bool more = (it + 1) < NTILES;

        // ---- issue next-iter A loads first (uniform issue; per-lane clamp) --
        float okm = 1.0f;
        if (more) {
            const int kn = (it + 1) * 32;
            const bool ok = (kn + q * 8) < KREAL;   // false only on tile 24, q>=2
            okm = ok ? 1.0f : 0.0f;
            const int koff = ok ? kn : 0;           // safe in-bounds address
            const float* p0 = arow0 + koff;
            f0a = *(const float4*)p0; f0b = *(const float4*)(p0 + 4);
        }

        // ---- issue DMA one tile ahead ----
        if (more) {
            const bf16* bs = bsrc + (size_t)(it + 1) * TILE_ELEMS;
            char* bd = (char*)&Bs[cur ^ 1][0] + wave * 5 * 1024;
            #pragma unroll
            for (int j = 0; j < 5; ++j) {
                __builtin_amdgcn_global_load_lds(
                    (const GLOBAL_AS void*)(bs + j * 512),
                    (LDS_AS void*)(bd + j * 1024), 16, 0, 0);
            }
        }

        // ---- MFMA on current tile: A[m=c][k=q*8+j], B row stride 80 B ----
        {
            const bf16* bb = &Bs[cur][0] + c * TROW + q * 8;
            #pragma unroll
            for (int nt = 0; nt < 16; ++nt) {
                bf16x8 b = *(const bf16x8*)(bb + nt * 16 * TROW);
                acc[nt] = __builtin_amdgcn_mfma_f32_16x16x32_bf16(a0, b, acc[nt], 0, 0, 0);
            }
        }

        // ---- convert prefetched A (waits on A loads AFTER compute) ----
        if (more) {
            a0[0] = (bf16)(f0a.x * okm); a0[1] = (bf16)(f0a.y * okm);
            a0[2] = (bf16)(f0a.z * okm); a0[3] = (bf16)(f0a.w * okm);
            a0[4] = (bf16)(f0b.x * okm); a0[5] = (bf16)(f0b.y * okm);
            a0[6] = (bf16)(f0b.z * okm); a0[7] = (bf16)(f0b.w * okm);
        }

        // ---- barrier: next tile resident; old buffer reads done ----
        if (more) {
            asm volatile("s_waitcnt vmcnt(0)" ::: "memory");
            __builtin_amdgcn_sched_barrier(0);
            __builtin_amdgcn_s_barrier();
            __builtin_amdgcn_sched_barrier(0);
        }
    }

    // ---- epilogue: h = relu(acc + b1); out = h @ w2 + b2 ----
    // C/D layout: col = lane&15 (= n within tile), row = q*4 + reg
    float bl[16];
    #pragma unroll
    for (int nt = 0; nt < 16; ++nt) bl[nt] = b1[nt * 16 + c];

    #pragma unroll
    for (int nt = 0; nt < 16; ++nt)
        #pragma unroll
        for (int r = 0; r < 4; ++r) {
            float v = acc[nt][r] + bl[nt];
            acc[nt][r] = v > 0.f ? v : 0.f;
        }

    #pragma unroll 1
    for (int j = 0; j < 10; ++j) {
        float wj[16];
        #pragma unroll
        for (int nt = 0; nt < 16; ++nt) wj[nt] = w2[(nt * 16 + c) * 10 + j];
        const float b2j = b2[j];
        #pragma unroll
        for (int r = 0; r < 4; ++r) {
            float s = 0.f;
            #pragma unroll
            for (int nt = 0; nt < 16; ++nt) s += acc[nt][r] * wj[nt];
            s += __shfl_xor(s, 1, 64);
            s += __shfl_xor(s, 2, 64);
            s += __shfl_xor(s, 4, 64);
            s += __shfl_xor(s, 8, 64);
            if (c == j) {
                const int row = row0 + wave * 16 + q * 4 + r;
                out[(size_t)row * 10 + j] = s + b2j;
            }
        }
    }
}

extern "C" void kernel_launch(void* const* d_in, const int* in_sizes, int n_in,
                              void* d_out, int out_size, void* d_ws, size_t ws_size,
                              hipStream_t stream) {
    const float* x  = (const float*)d_in[0];
    const float* wc = (const float*)d_in[1];
    const float* w1 = (const float*)d_in[2];
    const float* b1 = (const float*)d_in[3];
    const float* w2 = (const float*)d_in[4];
    const float* b2 = (const float*)d_in[5];
    float* out = (float*)d_out;
    bf16* W = (bf16*)d_ws;  // 25 * 10240 * 2 B = 500 KB scratch

    prep_w1tt<<<dim3(NTILES * TROW), dim3(256), 0, stream>>>(wc, w1, W);
    fused_mlp<<<dim3(65536 / 64), dim3(256), 0, stream>>>(x, W, b1, w2, b2, out);
}

// Round 5
// 312.522 us; speedup vs baseline: 1.0899x; 1.0899x over previous
//
#include <hip/hip_runtime.h>
#include <hip/hip_bf16.h>
#include <stdint.h>

typedef __bf16 bf16;
typedef __attribute__((ext_vector_type(8))) __bf16 bf16x8;
typedef __attribute__((ext_vector_type(4))) float f32x4;

#define KREAL 784
#define NTILES 25            // 25 k-tiles of 32
#define TROW   40            // row length in elements within a k-tile (32 + 8 pad)
#define TILE_ELEMS (256 * TROW)   // 10240 elements = 20 KB per k-tile

#define GLOBAL_AS __attribute__((address_space(1)))
#define LDS_AS    __attribute__((address_space(3)))

// ---------------------------------------------------------------------------
// Prep: fold 3x3 VALID cross-correlation into w1, emit k-tiled, row-padded:
//   W[tile][n][kk]  kk in [0,40), value for k = tile*32+kk when kk<32 & k<784,
//   else 0. The 80 B row stride makes the GEMM's ds_read_b128 bank-uniform,
//   and the pad lives in GLOBAL memory so global_load_lds's (wave-uniform
//   base + lane*16) rule still sees one contiguous region.
// ---------------------------------------------------------------------------
__global__ __launch_bounds__(256) void prep_w1tt(const float* __restrict__ w_conv,
                                                 const float* __restrict__ w1,
                                                 bf16* __restrict__ W) {
    const int tile = blockIdx.x / TROW;
    const int kk   = blockIdx.x % TROW;
    const int n    = threadIdx.x;
    const int k    = tile * 32 + kk;
    float s = 0.0f;
    if (kk < 32 && k < KREAL) {
        const int r = k / 28, c = k % 28;
        #pragma unroll
        for (int di = 0; di < 3; ++di) {
            const int i = r - di;
            if (i < 0 || i >= 26) continue;
            #pragma unroll
            for (int dj = 0; dj < 3; ++dj) {
                const int j = c - dj;
                if (j < 0 || j >= 26) continue;
                s += w_conv[di * 3 + dj] * w1[(i * 26 + j) * 256 + n];
            }
        }
    }
    W[(size_t)tile * TILE_ELEMS + n * TROW + kk] = (bf16)s;
}

// DPP-based cross-lane add: s + permuted(s), VALU-only (no DS pipe).
// Ctrl encodings (16-lane DPP rows on CDNA):
//   0xB1  = quad_perm[1,0,3,2]  -> lane ^ 1
//   0x4E  = quad_perm[2,3,0,1]  -> lane ^ 2
//   0x124 = row_ror:4           -> rotate by 4 within the 16-lane row
//   0x128 = row_ror:8           -> rotate by 8 == lane ^ 8 within the row
// R4 bug: 0x141 (row_half_mirror) is lane^7, NOT lane^8 — replaced by ror
// ring-reduction: after xor1+xor2 each quad holds a uniform quad-sum, so
// ror:4 adds the neighboring quad's sum and ror:8 the remaining two quads
// (direction-agnostic). Full 16-lane sum in 4 DPP adds, zero DS ops.
template <int CTRL>
__device__ __forceinline__ float dpp_add(float s) {
    int v = __builtin_amdgcn_update_dpp(0, __float_as_int(s), CTRL, 0xf, 0xf, false);
    return s + __int_as_float(v);
}

// ---------------------------------------------------------------------------
// Fused: out = relu(x @ W1' + b1) @ w2 + b2
// M=128/block, N=256 (full), BK=32, ONE barrier per K-iter  (R0 structure —
// best measured; R2 depth-2 pipelining and R3 M=64/TLP both ablated null or
// negative: the loop is LDS/B-movement-throughput-bound, structural at this
// tile shape).
//   A: global -> float regs (prefetched one iter ahead, cvt after MFMAs)
//   B: global_load_lds DMA into double-buffered Bs (20 KB/tile), issued one
//      iter ahead; barrier drain therefore only forces next-iter data.
// Epilogue: 256->10 on fp32 VALU. R3 measured 6.55M SQ_LDS_BANK_CONFLICT
// cycles tracking the shfl_xor count exactly -> all four reduce steps now
// DPP adds (VALU pipe). DS ops in epilogue: 320 -> 0 per wave.
// ---------------------------------------------------------------------------
__global__ __launch_bounds__(256, 2) void fused_mlp(
    const float* __restrict__ x,    // (65536, 784)
    const bf16*  __restrict__ W,    // k-tiled padded W1' (25*10240 bf16)
    const float* __restrict__ b1,   // (256)
    const float* __restrict__ w2,   // (256, 10)
    const float* __restrict__ b2,   // (10)
    float* __restrict__ out)        // (65536, 10)
{
    __shared__ bf16  Bs[2][TILE_ELEMS];  // 2 x 20 KB
    __shared__ float w2s[256][10];       // 10 KB
    __shared__ float b1s[256];
    __shared__ float b2s[10];

    const int t    = threadIdx.x;
    const int wave = t >> 6;
    const int lane = t & 63;
    const int c    = lane & 15;   // MFMA col / A-row within 16-tile
    const int q    = lane >> 4;   // MFMA quad (k-chunk selector)

    const int row0 = blockIdx.x * 128;

    // one-time stage of epilogue constants (pre-loop barrier publishes them)
    for (int i = t; i < 2560; i += 256) ((float*)w2s)[i] = w2[i];
    b1s[t] = b1[t];
    if (t < 10) b2s[t] = b2[t];

    // A: lane (c,q) owns rows (wave*32 + c) and (+16), k-chunk q*8..q*8+7
    const float* arow0 = x + (size_t)(row0 + wave * 32 + c) * KREAL + q * 8;
    const float* arow1 = arow0 + (size_t)16 * KREAL;
    // B DMA: wave w, instr j stages elements [(w*5+j)*512, +512) of the tile
    const bf16* bsrc = W + (size_t)(wave * 5) * 512 + lane * 8;

    f32x4 acc[2][16];
    #pragma unroll
    for (int mt = 0; mt < 2; ++mt)
        #pragma unroll
        for (int nt = 0; nt < 16; ++nt)
            acc[mt][nt] = (f32x4){0.f, 0.f, 0.f, 0.f};

    // ---- prologue: DMA tile 0, load+cvt A(0) ----
    #pragma unroll
    for (int j = 0; j < 5; ++j) {
        __builtin_amdgcn_global_load_lds(
            (const GLOBAL_AS void*)(bsrc + j * 512),
            (LDS_AS void*)((char*)&Bs[0][0] + (wave * 5 + j) * 1024), 16, 0, 0);
    }
    float4 f0a = *(const float4*)arow0, f0b = *(const float4*)(arow0 + 4);
    float4 f1a = *(const float4*)arow1, f1b = *(const float4*)(arow1 + 4);
    bf16x8 a0, a1;
    a0[0] = (bf16)f0a.x; a0[1] = (bf16)f0a.y; a0[2] = (bf16)f0a.z; a0[3] = (bf16)f0a.w;
    a0[4] = (bf16)f0b.x; a0[5] = (bf16)f0b.y; a0[6] = (bf16)f0b.z; a0[7] = (bf16)f0b.w;
    a1[0] = (bf16)f1a.x; a1[1] = (bf16)f1a.y; a1[2] = (bf16)f1a.z; a1[3] = (bf16)f1a.w;
    a1[4] = (bf16)f1b.x; a1[5] = (bf16)f1b.y; a1[6] = (bf16)f1b.z; a1[7] = (bf16)f1b.w;
    __syncthreads();   // tile 0 resident; w2s/b1s/b2s published

    #pragma unroll 1
    for (int it = 0; it < NTILES; ++it) {
        const int cur = it & 1;
        const bool more = (it + 1) < NTILES;

        // ---- prefetch next iter: B-DMA + A float loads (issued first) ----
        if (more) {
            const bf16* bs = bsrc + (size_t)(it + 1) * TILE_ELEMS;
            char* bd = (char*)&Bs[cur ^ 1][0] + wave * 5 * 1024;
            #pragma unroll
            for (int j = 0; j < 5; ++j) {
                __builtin_amdgcn_global_load_lds(
                    (const GLOBAL_AS void*)(bs + j * 512),
                    (LDS_AS void*)(bd + j * 1024), 16, 0, 0);
            }
            const int kn = (it + 1) * 32;
            if (kn + q * 8 < KREAL) {   // zero-guard (784 % 8 == 0)
                const float* p0 = arow0 + kn;
                const float* p1 = arow1 + kn;
                f0a = *(const float4*)p0; f0b = *(const float4*)(p0 + 4);
                f1a = *(const float4*)p1; f1b = *(const float4*)(p1 + 4);
            } else {
                f0a = f0b = f1a = f1b = (float4){0.f, 0.f, 0.f, 0.f};
            }
        }

        // ---- MFMA on current tile: A[m=c][k=q*8+j], B row stride 80 B ----
        #pragma unroll
        for (int nt = 0; nt < 16; ++nt) {
            bf16x8 b = *(const bf16x8*)&Bs[cur][(nt * 16 + c) * TROW + q * 8];
            acc[0][nt] = __builtin_amdgcn_mfma_f32_16x16x32_bf16(a0, b, acc[0][nt], 0, 0, 0);
            acc[1][nt] = __builtin_amdgcn_mfma_f32_16x16x32_bf16(a1, b, acc[1][nt], 0, 0, 0);
        }

        // ---- convert prefetched A (waits on A loads AFTER compute) ----
        if (more) {
            a0[0] = (bf16)f0a.x; a0[1] = (bf16)f0a.y; a0[2] = (bf16)f0a.z; a0[3] = (bf16)f0a.w;
            a0[4] = (bf16)f0b.x; a0[5] = (bf16)f0b.y; a0[6] = (bf16)f0b.z; a0[7] = (bf16)f0b.w;
            a1[0] = (bf16)f1a.x; a1[1] = (bf16)f1a.y; a1[2] = (bf16)f1a.z; a1[3] = (bf16)f1a.w;
            a1[4] = (bf16)f1b.x; a1[5] = (bf16)f1b.y; a1[6] = (bf16)f1b.z; a1[7] = (bf16)f1b.w;
        }

        __syncthreads();   // next tile resident; old buffer reads done
    }

    // ---- epilogue: h = relu(acc + b1); out = h @ w2 + b2 ----
    // C/D layout: col = lane&15 (= n within tile), row = q*4 + reg
    float bl[16];
    #pragma unroll
    for (int nt = 0; nt < 16; ++nt) bl[nt] = b1s[nt * 16 + c];

    #pragma unroll
    for (int mt = 0; mt < 2; ++mt)
        #pragma unroll
        for (int nt = 0; nt < 16; ++nt)
            #pragma unroll
            for (int r = 0; r < 4; ++r) {
                float v = acc[mt][nt][r] + bl[nt];
                acc[mt][nt][r] = v > 0.f ? v : 0.f;
            }

    #pragma unroll 1
    for (int j = 0; j < 10; ++j) {
        float wj[16];
        #pragma unroll
        for (int nt = 0; nt < 16; ++nt) wj[nt] = w2s[nt * 16 + c][j];
        const float b2j = b2s[j];
        #pragma unroll
        for (int mt = 0; mt < 2; ++mt)
            #pragma unroll
            for (int r = 0; r < 4; ++r) {
                float s = 0.f;
                #pragma unroll
                for (int nt = 0; nt < 16; ++nt) s += acc[mt][nt][r] * wj[nt];
                // 16-lane sum, all DPP (VALU pipe, no DS ops):
                s = dpp_add<0xB1>(s);    // lane ^ 1 (quad_perm)
                s = dpp_add<0x4E>(s);    // lane ^ 2 (quad_perm)
                s = dpp_add<0x124>(s);   // row_ror:4 — quad-sums are uniform,
                s = dpp_add<0x128>(s);   // row_ror:8 — ring-add all 4 quads
                if (c == j) {
                    const int row = row0 + wave * 32 + mt * 16 + q * 4 + r;
                    out[(size_t)row * 10 + j] = s + b2j;
                }
            }
    }
}

extern "C" void kernel_launch(void* const* d_in, const int* in_sizes, int n_in,
                              void* d_out, int out_size, void* d_ws, size_t ws_size,
                              hipStream_t stream) {
    const float* x  = (const float*)d_in[0];
    const float* wc = (const float*)d_in[1];
    const float* w1 = (const float*)d_in[2];
    const float* b1 = (const float*)d_in[3];
    const float* w2 = (const float*)d_in[4];
    const float* b2 = (const float*)d_in[5];
    float* out = (float*)d_out;
    bf16* W = (bf16*)d_ws;  // 25 * 10240 * 2 B = 500 KB scratch

    prep_w1tt<<<dim3(NTILES * TROW), dim3(256), 0, stream>>>(wc, w1, W);
    fused_mlp<<<dim3(65536 / 128), dim3(256), 0, stream>>>(x, W, b1, w2, b2, out);
}